// Round 2
// baseline (289.885 us; speedup 1.0000x reference)
//
#include <hip/hip_runtime.h>

// Head attention, B=4 T=4096 C=1024 H=64. Inputs/outputs are FLOAT32 buffers
// (reference dtypes); compute path converts to bf16 for MFMA, accumulates f32.
// scores = k @ q^T (reference quirk: k is the "query" side).

typedef __attribute__((ext_vector_type(8))) short short8;
typedef __attribute__((ext_vector_type(4))) float f32x4;
typedef unsigned short u16;

#define MFMA16(A, B, C) __builtin_amdgcn_mfma_f32_16x16x32_bf16((A), (B), (C), 0, 0, 0)

__device__ __forceinline__ u16 f2b(float f) {
    // fp32 -> bf16 round-to-nearest-even (finite values only here)
    unsigned int u = __builtin_bit_cast(unsigned int, f);
    u += 0x7fffu + ((u >> 16) & 1u);
    return (u16)(u >> 16);
}

// ---------- kernel 1: W convert+transpose -> Wt[192][1024] bf16
// rows: 0-63 = Wk^T, 64-127 = Wq^T, 128-191 = Wv^T
__global__ __launch_bounds__(256) void wt_kernel(const float* __restrict__ Wk,
                                                 const float* __restrict__ Wq,
                                                 const float* __restrict__ Wv,
                                                 u16* __restrict__ Wt) {
    int idx = blockIdx.x * 256 + threadIdx.x;   // < 196608 = 192*1024
    int k = idx & 1023;
    int nrow = idx >> 10;                        // 0..191
    const float* W = (nrow < 64) ? Wk : (nrow < 128 ? Wq : Wv);
    int n = nrow & 63;
    Wt[idx] = f2b(W[k * 64 + n]);
}

// ---------- kernel 2: projections. Kb/Qb row-major [B*T][64] bf16, Vt transposed [B][64][4096] bf16
__global__ __launch_bounds__(256) void proj_kernel(const float* __restrict__ x,
                                                   const u16* __restrict__ Wt,
                                                   u16* __restrict__ Kb,
                                                   u16* __restrict__ Qb,
                                                   u16* __restrict__ Vt) {
    __shared__ u16 tile[64][72];                 // +8 pad breaks bank conflicts
    const int tid = threadIdx.x;
    const int w = tid >> 6, lane = tid & 63, quad = lane >> 4, l16 = lane & 15;
    const int mbase = blockIdx.x * 64;           // 256 blocks over M=16384
    const int m = mbase + w * 16 + l16;          // A-frag row for this lane
    const int koff = quad * 8;

    f32x4 acc[12];
#pragma unroll
    for (int t = 0; t < 12; ++t) acc[t] = (f32x4)(0.0f);

    const float* xrow = x + (size_t)m * 1024;
    for (int kc = 0; kc < 32; ++kc) {            // K = 1024 in chunks of 32
        float4 f0 = *(const float4*)(xrow + kc * 32 + koff);
        float4 f1 = *(const float4*)(xrow + kc * 32 + koff + 4);
        short8 a;
        a[0] = f2b(f0.x); a[1] = f2b(f0.y); a[2] = f2b(f0.z); a[3] = f2b(f0.w);
        a[4] = f2b(f1.x); a[5] = f2b(f1.y); a[6] = f2b(f1.z); a[7] = f2b(f1.w);
#pragma unroll
        for (int t = 0; t < 12; ++t) {           // t = p*4 + ntile; Wt row = t*16 + l16
            short8 b = *(const short8*)(Wt + (size_t)(t * 16 + l16) * 1024 + kc * 32 + koff);
            acc[t] = MFMA16(a, b, acc[t]);
        }
    }

    const int trow = w * 16 + quad * 4;
    // K and Q: row-major epilogue via LDS for coalesced bf16 stores
    for (int p = 0; p < 2; ++p) {
        __syncthreads();
#pragma unroll
        for (int nt = 0; nt < 4; ++nt)
#pragma unroll
            for (int reg = 0; reg < 4; ++reg)
                tile[trow + reg][nt * 16 + l16] = f2b(acc[p * 4 + nt][reg]);
        __syncthreads();
        u16* dst = (p == 0) ? Kb : Qb;
#pragma unroll
        for (int c = 0; c < 2; ++c) {
            int linear = tid + c * 256;
            int row = linear >> 3, col8 = (linear & 7) << 3;
            *(short8*)(dst + (size_t)(mbase + row) * 64 + col8) = *(short8*)&tile[row][col8];
        }
    }
    // V transposed: tile[h][t_local]
    __syncthreads();
#pragma unroll
    for (int nt = 0; nt < 4; ++nt)
#pragma unroll
        for (int reg = 0; reg < 4; ++reg)
            tile[nt * 16 + l16][trow + reg] = f2b(acc[8 + nt][reg]);
    __syncthreads();
    const int b = mbase >> 12, t0b = mbase & 4095;
#pragma unroll
    for (int c = 0; c < 2; ++c) {
        int linear = tid + c * 256;
        int h = linear >> 3, col8 = (linear & 7) << 3;
        *(short8*)(Vt + ((size_t)(b * 64 + h) << 12) + t0b + col8) = *(short8*)&tile[h][col8];
    }
}

// ---------- kernel 3: flash-style causal attention, S = Kb @ Qb^T * 0.125, O = softmax(S) @ V
__global__ __launch_bounds__(256) void attn_kernel(const u16* __restrict__ Kb,
                                                   const u16* __restrict__ Qb,
                                                   const u16* __restrict__ Vt,
                                                   float* __restrict__ out) {
    __shared__ u16 Qs[64][72];
    __shared__ u16 Vs[64][72];
    __shared__ u16 Ps[64][72];
    const int tid = threadIdx.x;
    const int w = tid >> 6, lane = tid & 63, quad = lane >> 4, l16 = lane & 15;
    const int tile = 63 - blockIdx.x;            // biggest t-tiles launch first
    const int b = blockIdx.y;
    const int t0 = tile * 64;

    // A-fragments of K rows (this wave's 16 t-rows), K-dim = h (64 -> 2 frags)
    short8 aK[2];
#pragma unroll
    for (int kk = 0; kk < 2; ++kk)
        aK[kk] = *(const short8*)(Kb + (size_t)((b << 12) + t0 + w * 16 + l16) * 64 + kk * 32 + quad * 8);

    float m_s[4], l_s[4];
    f32x4 O[4];
#pragma unroll
    for (int r = 0; r < 4; ++r) { m_s[r] = -1e30f; l_s[r] = 0.0f; }
#pragma unroll
    for (int nt = 0; nt < 4; ++nt) O[nt] = (f32x4)(0.0f);

    const int trow = w * 16 + quad * 4;          // + reg = local t row
    const int tglob = t0 + trow;                 // + reg = global t

    for (int st = 0; st <= tile; ++st) {
        const int s0 = st * 64;
        __syncthreads();                          // protect Qs/Vs from previous PV reads
#pragma unroll
        for (int c = 0; c < 2; ++c) {
            int linear = tid + c * 256;
            int row = linear >> 3, col8 = (linear & 7) << 3;
            *(short8*)&Qs[row][col8] = *(const short8*)(Qb + (size_t)((b << 12) + s0 + row) * 64 + col8);
            *(short8*)&Vs[row][col8] = *(const short8*)(Vt + ((size_t)((b << 6) + row) << 12) + s0 + col8);
        }
        __syncthreads();

        // S tile: rows = this wave's 16 t, cols = 64 s
        f32x4 sc[4];
#pragma unroll
        for (int nt = 0; nt < 4; ++nt) sc[nt] = (f32x4)(0.0f);
#pragma unroll
        for (int kk = 0; kk < 2; ++kk)
#pragma unroll
            for (int nt = 0; nt < 4; ++nt) {
                short8 bq = *(const short8*)&Qs[nt * 16 + l16][kk * 32 + quad * 8];
                sc[nt] = MFMA16(aK[kk], bq, sc[nt]);
            }

        // scale + causal mask (diagonal tile only) + row max
        float mx[4] = {-1e30f, -1e30f, -1e30f, -1e30f};
#pragma unroll
        for (int nt = 0; nt < 4; ++nt) {
            int sg = s0 + nt * 16 + l16;
#pragma unroll
            for (int reg = 0; reg < 4; ++reg) {
                float v = sc[nt][reg] * 0.125f;
                if (st == tile && sg > tglob + reg) v = -1e30f;
                sc[nt][reg] = v;
                mx[reg] = fmaxf(mx[reg], v);
            }
        }
#pragma unroll
        for (int reg = 0; reg < 4; ++reg) {       // row max across the 16-lane col group
            float v = mx[reg];
            v = fmaxf(v, __shfl_xor(v, 1));
            v = fmaxf(v, __shfl_xor(v, 2));
            v = fmaxf(v, __shfl_xor(v, 4));
            v = fmaxf(v, __shfl_xor(v, 8));
            mx[reg] = v;
        }
        float alpha[4], rs[4];
#pragma unroll
        for (int reg = 0; reg < 4; ++reg) {
            float mn = fmaxf(m_s[reg], mx[reg]);
            alpha[reg] = __expf(m_s[reg] - mn);
            m_s[reg] = mn;
            l_s[reg] *= alpha[reg];
            rs[reg] = 0.0f;
        }
#pragma unroll
        for (int nt = 0; nt < 4; ++nt)
#pragma unroll
            for (int reg = 0; reg < 4; ++reg) {
                float p = __expf(sc[nt][reg] - m_s[reg]);
                rs[reg] += p;
                Ps[trow + reg][nt * 16 + l16] = f2b(p);   // C-layout -> LDS
            }
#pragma unroll
        for (int reg = 0; reg < 4; ++reg) {
            float v = rs[reg];
            v += __shfl_xor(v, 1);
            v += __shfl_xor(v, 2);
            v += __shfl_xor(v, 4);
            v += __shfl_xor(v, 8);
            l_s[reg] += v;
        }
#pragma unroll
        for (int nt = 0; nt < 4; ++nt)
#pragma unroll
            for (int reg = 0; reg < 4; ++reg)
                O[nt][reg] *= alpha[reg];

        __syncthreads();                           // Ps visible before PV reads
        // PV: A = P (this wave's rows, A-layout from LDS), B = V^T tile
#pragma unroll
        for (int kk = 0; kk < 2; ++kk) {
            short8 ap = *(const short8*)&Ps[w * 16 + l16][kk * 32 + quad * 8];
#pragma unroll
            for (int nt = 0; nt < 4; ++nt) {
                short8 bv = *(const short8*)&Vs[nt * 16 + l16][kk * 32 + quad * 8];
                O[nt] = MFMA16(ap, bv, O[nt]);
            }
        }
    }

    // epilogue: O / l -> f32, direct stores (C-layout: row tglob+reg, col nt*16+l16)
#pragma unroll
    for (int nt = 0; nt < 4; ++nt)
#pragma unroll
        for (int reg = 0; reg < 4; ++reg)
            out[(size_t)((b << 12) + tglob + reg) * 64 + nt * 16 + l16] = O[nt][reg] / l_s[reg];
}

extern "C" void kernel_launch(void* const* d_in, const int* in_sizes, int n_in,
                              void* d_out, int out_size, void* d_ws, size_t ws_size,
                              hipStream_t stream) {
    const float* x  = (const float*)d_in[0];   // [4,4096,1024] f32
    const float* Wk = (const float*)d_in[1];   // [1024,64] f32
    const float* Wq = (const float*)d_in[2];
    const float* Wv = (const float*)d_in[3];

    u16* ws = (u16*)d_ws;
    u16* Wt = ws;                          // 192*1024        = 196608 elems bf16
    u16* Kb = Wt + 196608;                 // 16384*64        = 1048576
    u16* Qb = Kb + 1048576;
    u16* Vt = Qb + 1048576;                // [4][64][4096]
    // total ws use: (196608 + 3*1048576)*2 B ~= 6.8 MB

    wt_kernel<<<768, 256, 0, stream>>>(Wk, Wq, Wv, Wt);
    proj_kernel<<<256, 256, 0, stream>>>(x, Wt, Kb, Qb, Vt);
    attn_kernel<<<dim3(64, 4), 256, 0, stream>>>(Kb, Qb, Vt, (float*)d_out);
}

// Round 3
// 218.110 us; speedup vs baseline: 1.3291x; 1.3291x over previous
//
#include <hip/hip_runtime.h>

// Head attention, B=4 T=4096 C=1024 H=64. f32 in/out, bf16 MFMA compute.
// scores = k @ q^T (reference quirk). Split-S flash attention + combine.

typedef __attribute__((ext_vector_type(8))) short short8;
typedef __attribute__((ext_vector_type(4))) float f32x4;
typedef unsigned short u16;

#define MFMA16(A, B, C) __builtin_amdgcn_mfma_f32_16x16x32_bf16((A), (B), (C), 0, 0, 0)

__device__ __forceinline__ u16 f2b(float f) {
    unsigned int u = __builtin_bit_cast(unsigned int, f);
    u += 0x7fffu + ((u >> 16) & 1u);
    return (u16)(u >> 16);
}
__device__ __forceinline__ float b2f(u16 v) {
    return __builtin_bit_cast(float, (unsigned int)v << 16);
}

// ---------- kernel 1: W convert+transpose -> Wt[192][1024] bf16 (rows 0-63 Wk^T, 64-127 Wq^T, 128-191 Wv^T)
__global__ __launch_bounds__(256) void wt_kernel(const float* __restrict__ Wk,
                                                 const float* __restrict__ Wq,
                                                 const float* __restrict__ Wv,
                                                 u16* __restrict__ Wt) {
    __shared__ u16 t[64][65];
    const int mat = blockIdx.x >> 4;     // 0..2
    const int rt  = blockIdx.x & 15;     // k-tile (64 rows of W)
    const float* W = (mat == 0) ? Wk : (mat == 1 ? Wq : Wv);
    const int tid = threadIdx.x;
#pragma unroll
    for (int i = 0; i < 16; ++i) {
        int lin = i * 256 + tid, r = lin >> 6, c = lin & 63;
        t[c][r] = f2b(W[(size_t)(rt * 64 + r) * 64 + c]);   // coalesced read
    }
    __syncthreads();
#pragma unroll
    for (int i = 0; i < 16; ++i) {
        int lin = i * 256 + tid, n = lin >> 6, k = lin & 63;
        Wt[(size_t)(mat * 64 + n) * 1024 + rt * 64 + k] = t[n][k];  // coalesced write
    }
}

// ---------- kernel 2: projections. Kb/Qb [B*T][64] bf16, Vt [B][64][4096] bf16.
// Wt K-slice staged in double-buffered LDS; x prefetched in registers.
__global__ __launch_bounds__(256) void proj_kernel(const float* __restrict__ x,
                                                   const u16* __restrict__ Wt,
                                                   u16* __restrict__ Kb,
                                                   u16* __restrict__ Qb,
                                                   u16* __restrict__ Vt) {
    __shared__ u16 smem[2 * 192 * 36];               // 27.6 KB; pad 32->36 u16/row: conflict-free b128
    const int tid = threadIdx.x;
    const int w = tid >> 6, lane = tid & 63, quad = lane >> 4, l16 = lane & 15;
    const int mbase = blockIdx.x * 64;
    const int m = mbase + w * 16 + l16;
    const int koff = quad * 8;

    f32x4 acc[12];
#pragma unroll
    for (int t = 0; t < 12; ++t) acc[t] = (f32x4)(0.0f);

    const float* xrow = x + (size_t)m * 1024 + koff;
    const int u0 = tid, u1 = tid + 256, u2 = tid + 512;  // 768 16B-units = [192][32]

    // stage kc=0 into buf 0
    {
        short8 s0 = *(const short8*)(Wt + (size_t)(u0 >> 2) * 1024 + (u0 & 3) * 8);
        short8 s1 = *(const short8*)(Wt + (size_t)(u1 >> 2) * 1024 + (u1 & 3) * 8);
        short8 s2 = *(const short8*)(Wt + (size_t)(u2 >> 2) * 1024 + (u2 & 3) * 8);
        *(short8*)(smem + (u0 >> 2) * 36 + (u0 & 3) * 8) = s0;
        *(short8*)(smem + (u1 >> 2) * 36 + (u1 & 3) * 8) = s1;
        *(short8*)(smem + (u2 >> 2) * 36 + (u2 & 3) * 8) = s2;
    }
    float4 c0 = *(const float4*)(xrow);
    float4 c1 = *(const float4*)(xrow + 4);
    __syncthreads();

    for (int kc = 0; kc < 32; ++kc) {
        const int cur = kc & 1, nxt = cur ^ 1;
        short8 p0, p1, p2;
        float4 n0, n1;
        if (kc < 31) {                                // prefetch kc+1
            p0 = *(const short8*)(Wt + (size_t)(u0 >> 2) * 1024 + (kc + 1) * 32 + (u0 & 3) * 8);
            p1 = *(const short8*)(Wt + (size_t)(u1 >> 2) * 1024 + (kc + 1) * 32 + (u1 & 3) * 8);
            p2 = *(const short8*)(Wt + (size_t)(u2 >> 2) * 1024 + (kc + 1) * 32 + (u2 & 3) * 8);
            n0 = *(const float4*)(xrow + (kc + 1) * 32);
            n1 = *(const float4*)(xrow + (kc + 1) * 32 + 4);
        }
        short8 a;
        a[0] = f2b(c0.x); a[1] = f2b(c0.y); a[2] = f2b(c0.z); a[3] = f2b(c0.w);
        a[4] = f2b(c1.x); a[5] = f2b(c1.y); a[6] = f2b(c1.z); a[7] = f2b(c1.w);
        const u16* base = smem + cur * 6912;
#pragma unroll
        for (int t = 0; t < 12; ++t) {
            short8 b = *(const short8*)(base + (t * 16 + l16) * 36 + koff);
            acc[t] = MFMA16(a, b, acc[t]);
        }
        if (kc < 31) {
            u16* nb = smem + nxt * 6912;
            *(short8*)(nb + (u0 >> 2) * 36 + (u0 & 3) * 8) = p0;
            *(short8*)(nb + (u1 >> 2) * 36 + (u1 & 3) * 8) = p1;
            *(short8*)(nb + (u2 >> 2) * 36 + (u2 & 3) * 8) = p2;
            __syncthreads();
            c0 = n0; c1 = n1;
        }
    }

    // epilogue (alias a 64x72 tile onto smem)
    u16 (*tile)[72] = (u16(*)[72])smem;
    const int trow = w * 16 + quad * 4;
    for (int p = 0; p < 2; ++p) {
        __syncthreads();
#pragma unroll
        for (int nt = 0; nt < 4; ++nt)
#pragma unroll
            for (int reg = 0; reg < 4; ++reg)
                tile[trow + reg][nt * 16 + l16] = f2b(acc[p * 4 + nt][reg]);
        __syncthreads();
        u16* dst = (p == 0) ? Kb : Qb;
#pragma unroll
        for (int c = 0; c < 2; ++c) {
            int linear = tid + c * 256;
            int row = linear >> 3, col8 = (linear & 7) << 3;
            *(short8*)(dst + (size_t)(mbase + row) * 64 + col8) = *(short8*)&tile[row][col8];
        }
    }
    __syncthreads();
#pragma unroll
    for (int nt = 0; nt < 4; ++nt)
#pragma unroll
        for (int reg = 0; reg < 4; ++reg)
            tile[nt * 16 + l16][trow + reg] = f2b(acc[8 + nt][reg]);
    __syncthreads();
    const int bb = mbase >> 12, t0b = mbase & 4095;
#pragma unroll
    for (int c = 0; c < 2; ++c) {
        int linear = tid + c * 256;
        int h = linear >> 3, col8 = (linear & 7) << 3;
        *(short8*)(Vt + ((size_t)(bb * 64 + h) << 12) + t0b + col8) = *(short8*)&tile[h][col8];
    }
}

// ---------- kernel 3: split-S flash attention pass 1.
// grid (tile=64, chunk=8, batch=4); chunk c covers s-tiles [8c, 8c+7] clipped to causal.
// Writes unnormalized partial O (bf16) + m,l (f32) per slot.
__global__ __launch_bounds__(256) void attn_kernel(const u16* __restrict__ Kb,
                                                   const u16* __restrict__ Qb,
                                                   const u16* __restrict__ Vt,
                                                   u16* __restrict__ Op,
                                                   float* __restrict__ Ml) {
    const int tile = blockIdx.x, chunk = blockIdx.y, b = blockIdx.z;
    if (chunk * 8 > tile) return;
    __shared__ u16 Qs[64][72];
    __shared__ u16 Vs[64][72];
    __shared__ u16 Ps[64][72];
    const int tid = threadIdx.x;
    const int w = tid >> 6, lane = tid & 63, quad = lane >> 4, l16 = lane & 15;
    const int t0 = tile * 64;
    const int stBeg = chunk * 8;
    const int stEnd = min(chunk * 8 + 7, tile);

    short8 aK[2];
#pragma unroll
    for (int kk = 0; kk < 2; ++kk)
        aK[kk] = *(const short8*)(Kb + (size_t)((b << 12) + t0 + w * 16 + l16) * 64 + kk * 32 + quad * 8);

    float m_s[4], l_s[4];
    f32x4 O[4];
#pragma unroll
    for (int r = 0; r < 4; ++r) { m_s[r] = -1e30f; l_s[r] = 0.0f; }
#pragma unroll
    for (int nt = 0; nt < 4; ++nt) O[nt] = (f32x4)(0.0f);

    const int trow = w * 16 + quad * 4;
    const int tglob = t0 + trow;

    for (int st = stBeg; st <= stEnd; ++st) {
        const int s0 = st * 64;
        __syncthreads();
#pragma unroll
        for (int c = 0; c < 2; ++c) {
            int linear = tid + c * 256;
            int row = linear >> 3, col8 = (linear & 7) << 3;
            *(short8*)&Qs[row][col8] = *(const short8*)(Qb + (size_t)((b << 12) + s0 + row) * 64 + col8);
            *(short8*)&Vs[row][col8] = *(const short8*)(Vt + ((size_t)((b << 6) + row) << 12) + s0 + col8);
        }
        __syncthreads();

        f32x4 sc[4];
#pragma unroll
        for (int nt = 0; nt < 4; ++nt) sc[nt] = (f32x4)(0.0f);
#pragma unroll
        for (int kk = 0; kk < 2; ++kk)
#pragma unroll
            for (int nt = 0; nt < 4; ++nt) {
                short8 bq = *(const short8*)&Qs[nt * 16 + l16][kk * 32 + quad * 8];
                sc[nt] = MFMA16(aK[kk], bq, sc[nt]);
            }

        float mx[4] = {-1e30f, -1e30f, -1e30f, -1e30f};
#pragma unroll
        for (int nt = 0; nt < 4; ++nt) {
            int sg = s0 + nt * 16 + l16;
#pragma unroll
            for (int reg = 0; reg < 4; ++reg) {
                float v = sc[nt][reg] * 0.125f;
                if (st == tile && sg > tglob + reg) v = -1e30f;
                sc[nt][reg] = v;
                mx[reg] = fmaxf(mx[reg], v);
            }
        }
#pragma unroll
        for (int reg = 0; reg < 4; ++reg) {
            float v = mx[reg];
            v = fmaxf(v, __shfl_xor(v, 1));
            v = fmaxf(v, __shfl_xor(v, 2));
            v = fmaxf(v, __shfl_xor(v, 4));
            v = fmaxf(v, __shfl_xor(v, 8));
            mx[reg] = v;
        }
        float alpha[4], rs[4];
#pragma unroll
        for (int reg = 0; reg < 4; ++reg) {
            float mn = fmaxf(m_s[reg], mx[reg]);
            alpha[reg] = __expf(m_s[reg] - mn);
            m_s[reg] = mn;
            l_s[reg] *= alpha[reg];
            rs[reg] = 0.0f;
        }
#pragma unroll
        for (int nt = 0; nt < 4; ++nt)
#pragma unroll
            for (int reg = 0; reg < 4; ++reg) {
                float p = __expf(sc[nt][reg] - m_s[reg]);
                rs[reg] += p;
                Ps[trow + reg][nt * 16 + l16] = f2b(p);
            }
#pragma unroll
        for (int reg = 0; reg < 4; ++reg) {
            float v = rs[reg];
            v += __shfl_xor(v, 1);
            v += __shfl_xor(v, 2);
            v += __shfl_xor(v, 4);
            v += __shfl_xor(v, 8);
            l_s[reg] += v;
        }
#pragma unroll
        for (int nt = 0; nt < 4; ++nt)
#pragma unroll
            for (int reg = 0; reg < 4; ++reg)
                O[nt][reg] *= alpha[reg];

        __syncthreads();
#pragma unroll
        for (int kk = 0; kk < 2; ++kk) {
            short8 ap = *(const short8*)&Ps[w * 16 + l16][kk * 32 + quad * 8];
#pragma unroll
            for (int nt = 0; nt < 4; ++nt) {
                short8 bv = *(const short8*)&Vs[nt * 16 + l16][kk * 32 + quad * 8];
                O[nt] = MFMA16(ap, bv, O[nt]);
            }
        }
    }

    // write partial: O unnormalized (bf16), m,l (f32)
    const int slot = ((b * 64 + tile) * 8 + chunk);
    if (l16 == 0) {
#pragma unroll
        for (int reg = 0; reg < 4; ++reg) {
            Ml[(size_t)slot * 128 + trow + reg]      = m_s[reg];
            Ml[(size_t)slot * 128 + 64 + trow + reg] = l_s[reg];
        }
    }
#pragma unroll
    for (int nt = 0; nt < 4; ++nt)
#pragma unroll
        for (int reg = 0; reg < 4; ++reg)
            Op[(size_t)slot * 4096 + (size_t)(trow + reg) * 64 + nt * 16 + l16] = f2b(O[nt][reg]);
}

// ---------- kernel 4: combine partials -> out f32
__global__ __launch_bounds__(256) void combine_kernel(const u16* __restrict__ Op,
                                                      const float* __restrict__ Ml,
                                                      float* __restrict__ out) {
    const int tid = threadIdx.x, col = tid & 63, r0 = tid >> 6;
    const int tile = blockIdx.x >> 2, rg = blockIdx.x & 3, b = blockIdx.y;
    const int nch = tile / 8 + 1;                    // active chunks for this tile
    const int slotBase = (b * 64 + tile) * 8;
#pragma unroll
    for (int i = 0; i < 4; ++i) {
        const int row = rg * 16 + r0 + 4 * i;        // 0..63 within tile
        float m[8], l[8];
        float M = -1e30f;
        for (int c = 0; c < nch; ++c) {
            m[c] = Ml[(size_t)(slotBase + c) * 128 + row];
            l[c] = Ml[(size_t)(slotBase + c) * 128 + 64 + row];
            M = fmaxf(M, m[c]);
        }
        float L = 0.0f, acc = 0.0f;
        for (int c = 0; c < nch; ++c) {
            float wgt = __expf(m[c] - M);
            L += wgt * l[c];
            acc += wgt * b2f(Op[(size_t)(slotBase + c) * 4096 + (size_t)row * 64 + col]);
        }
        out[((size_t)(b << 12) + tile * 64 + row) * 64 + col] = acc / L;
    }
}

extern "C" void kernel_launch(void* const* d_in, const int* in_sizes, int n_in,
                              void* d_out, int out_size, void* d_ws, size_t ws_size,
                              hipStream_t stream) {
    const float* x  = (const float*)d_in[0];
    const float* Wk = (const float*)d_in[1];
    const float* Wq = (const float*)d_in[2];
    const float* Wv = (const float*)d_in[3];

    u16* ws = (u16*)d_ws;
    u16* Wt = ws;                           // 196608 u16
    u16* Kb = Wt + 196608;                  // 1048576
    u16* Qb = Kb + 1048576;
    u16* Vt = Qb + 1048576;                 // 1048576
    u16* Op = Vt + 1048576;                 // 2048 slots * 4096 = 8388608 u16
    float* Ml = (float*)(Op + 8388608);     // 2048 * 128 f32 = 1 MB
    // total ws ~24.5 MB

    wt_kernel<<<48, 256, 0, stream>>>(Wk, Wq, Wv, Wt);
    proj_kernel<<<256, 256, 0, stream>>>(x, Wt, Kb, Qb, Vt);
    attn_kernel<<<dim3(64, 8, 4), 256, 0, stream>>>(Kb, Qb, Vt, Op, Ml);
    combine_kernel<<<dim3(256, 4), 256, 0, stream>>>(Op, Ml, (float*)d_out);
}